// Round 1
// baseline (481.654 us; speedup 1.0000x reference)
//
#include <hip/hip_runtime.h>
#include <math.h>

#define B_ 16
#define T_ 12
#define N_ 1024
#define D_ 64
#define HS_ 16
#define HT_ 64
#define TT_ 192
#define BT_ 192   // B_*T_

__device__ __forceinline__ float lrelu_(float v){ return v > 0.f ? v : 0.01f*v; }

__device__ __forceinline__ float wredsum(float v){
    #pragma unroll
    for (int m = 1; m < 64; m <<= 1) v += __shfl_xor(v, m, 64);
    return v;
}

// ---------------------------------------------------------------------------
// P = squash(x @ W_p^T + b_p)   [BT, N, D]  (wave per row, W row in registers)
// ---------------------------------------------------------------------------
__global__ __launch_bounds__(256) void k_P(const float* __restrict__ x,
        const float* __restrict__ Wp, const float* __restrict__ bp,
        float* __restrict__ P){
    __shared__ __align__(16) float xsh[4][64];
    int w = threadIdx.x >> 6, d = threadIdx.x & 63;
    float wr[64];
    #pragma unroll
    for (int k4 = 0; k4 < 16; ++k4){
        float4 t = reinterpret_cast<const float4*>(Wp + d*64)[k4];
        wr[4*k4+0]=t.x; wr[4*k4+1]=t.y; wr[4*k4+2]=t.z; wr[4*k4+3]=t.w;
    }
    float bpd = bp[d];
    long base = (long)blockIdx.x * 64;
    for (int r = 0; r < 16; ++r){
        long row = base + w*16 + r;
        float xv = x[row*64 + d];
        __syncthreads();              // previous iteration's reads complete
        xsh[w][d] = xv;
        __syncthreads();
        float y = bpd;
        #pragma unroll
        for (int k4 = 0; k4 < 16; ++k4){
            float4 xc = reinterpret_cast<const float4*>(&xsh[w][0])[k4];
            y += xc.x*wr[4*k4] + xc.y*wr[4*k4+1] + xc.z*wr[4*k4+2] + xc.w*wr[4*k4+3];
        }
        float sn = wredsum(y*y);
        float sc = (sn/(1.f+sn))/(sqrtf(sn)+1e-8f);
        P[row*64+d] = y*sc;
    }
}

// ---------------------------------------------------------------------------
// dadj[bt,h,n] = sum_e teb[bt,e]*adj[e,h,n]
// ---------------------------------------------------------------------------
__global__ __launch_bounds__(256) void k_dadj(const float* __restrict__ teb,
        const float* __restrict__ adj, float* __restrict__ dadj){
    int bt = blockIdx.x, h = blockIdx.y;
    int n4 = threadIdx.x;
    float tl[16];
    #pragma unroll
    for (int e = 0; e < 16; ++e) tl[e] = teb[bt*16+e];
    float4 acc = {0.f,0.f,0.f,0.f};
    #pragma unroll
    for (int e = 0; e < 16; ++e){
        float4 a = reinterpret_cast<const float4*>(adj + ((long)e*HS_+h)*N_)[n4];
        acc.x += tl[e]*a.x; acc.y += tl[e]*a.y; acc.z += tl[e]*a.z; acc.w += tl[e]*a.w;
    }
    reinterpret_cast<float4*>(dadj + ((long)bt*HS_+h)*N_)[n4] = acc;
}

// ---------------------------------------------------------------------------
// Routing contraction. Per block (one bt):
//   c[h,n] = softmax_h(src1 (+src2))
//   t[h,d] = sum_n c[h,n]*P[n,d]
//   mode 0: out = squash(t)                    (test1 -> v1)
//   mode 1: out = squash(v1 .* t)              (routing v)
//   mode 2: out = t raw (=s), write c to cout  (final)
// ---------------------------------------------------------------------------
__global__ __launch_bounds__(256) void k_route(const float* __restrict__ src1,
        const float* __restrict__ src2, const float* __restrict__ P,
        const float* __restrict__ v1in, float* __restrict__ outv,
        float* __restrict__ cout, int mode){
    __shared__ __align__(16) float Pl[128*65];
    __shared__ __align__(16) float cch[128*20];
    int bt = blockIdx.x;
    int t = threadIdx.x, w = t>>6, d = t&63;
    float acc[4] = {0.f,0.f,0.f,0.f};
    const float* s1 = src1 + (long)bt*HS_*N_;
    const float* s2 = src2 ? src2 + (long)bt*HS_*N_ : (const float*)0;
    for (int c0 = 0; c0 < N_; c0 += 128){
        // stage P chunk [128][64] -> Pl padded 65
        #pragma unroll
        for (int j = 0; j < 8; ++j){
            int f4 = j*256 + t;
            int r = f4>>4, dd = (f4&15)*4;
            float4 pv = reinterpret_cast<const float4*>(P + ((long)bt*N_ + c0 + r)*64)[f4&15];
            Pl[r*65+dd]   = pv.x; Pl[r*65+dd+1] = pv.y;
            Pl[r*65+dd+2] = pv.z; Pl[r*65+dd+3] = pv.w;
        }
        // softmax over h for this chunk of n
        if (t < 128){
            int n = c0 + t;
            float sv[16];
            #pragma unroll
            for (int h = 0; h < 16; ++h){
                float v = s1[h*N_+n];
                if (s2) v += s2[h*N_+n];
                sv[h] = v;
            }
            float M = sv[0];
            #pragma unroll
            for (int h = 1; h < 16; ++h) M = fmaxf(M, sv[h]);
            float S = 0.f; float ev[16];
            #pragma unroll
            for (int h = 0; h < 16; ++h){ ev[h] = expf(sv[h]-M); S += ev[h]; }
            float inv = 1.f/S;
            #pragma unroll
            for (int h = 0; h < 16; ++h){
                float cv = ev[h]*inv;
                cch[t*20 + h] = cv;
                if (mode == 2) cout[((long)bt*HS_+h)*N_ + n] = cv;
            }
        }
        __syncthreads();
        // wave w accumulates h = 4w..4w+3, lane d
        #pragma unroll 4
        for (int nl = 0; nl < 128; ++nl){
            float4 cc = *reinterpret_cast<const float4*>(&cch[nl*20 + 4*w]);
            float p = Pl[nl*65 + d];
            acc[0] += cc.x*p; acc[1] += cc.y*p; acc[2] += cc.z*p; acc[3] += cc.w*p;
        }
        __syncthreads();
    }
    int h0 = 4*w;
    if (mode == 2){
        #pragma unroll
        for (int i = 0; i < 4; ++i)
            outv[((long)bt*HS_ + h0+i)*64 + d] = acc[i];
    } else {
        #pragma unroll
        for (int i = 0; i < 4; ++i){
            float q = acc[i];
            if (mode == 1) q *= v1in[((long)bt*HS_ + h0+i)*64 + d];
            float sn = wredsum(q*q);
            float sc = (sn/(1.f+sn))/(sqrtf(sn)+1e-8f);
            outv[((long)bt*HS_ + h0+i)*64 + d] = q*sc;
        }
    }
}

// ---------------------------------------------------------------------------
// b[h,n] += sum_d v[h,d]*P[n,d]
// ---------------------------------------------------------------------------
__global__ __launch_bounds__(256) void k_bupd(const float* __restrict__ P,
        const float* __restrict__ vv, float* __restrict__ bbuf){
    __shared__ __align__(16) float Pl[128*65];
    __shared__ __align__(16) float vl[16*64];
    int bt = blockIdx.x, ch = blockIdx.y;
    int t = threadIdx.x;
    int n0 = ch*128;
    #pragma unroll
    for (int j = 0; j < 8; ++j){
        int f4 = j*256 + t;
        int r = f4>>4, dd = (f4&15)*4;
        float4 pv = reinterpret_cast<const float4*>(P + ((long)bt*N_ + n0 + r)*64)[f4&15];
        Pl[r*65+dd]   = pv.x; Pl[r*65+dd+1] = pv.y;
        Pl[r*65+dd+2] = pv.z; Pl[r*65+dd+3] = pv.w;
    }
    #pragma unroll
    for (int j = 0; j < 4; ++j) vl[j*256+t] = vv[(long)bt*HS_*64 + j*256 + t];
    __syncthreads();
    int nl = t & 127, hg = t>>7;
    float acc[8] = {0.f,0.f,0.f,0.f,0.f,0.f,0.f,0.f};
    for (int d = 0; d < 64; ++d){
        float p = Pl[nl*65+d];
        #pragma unroll
        for (int j = 0; j < 8; ++j) acc[j] += p * vl[(hg*8+j)*64 + d];
    }
    #pragma unroll
    for (int j = 0; j < 8; ++j){
        long idx = ((long)bt*HS_ + hg*8 + j)*N_ + n0 + nl;
        bbuf[idx] += acc[j];
    }
}

// ---------------------------------------------------------------------------
// dyn[b,h,k] = sum_e time_eb[b,e]*t_adj[e,h,k]
// ---------------------------------------------------------------------------
__global__ __launch_bounds__(192) void k_dyn(const float* __restrict__ timeb,
        const float* __restrict__ tadj, float* __restrict__ dyn){
    int b = blockIdx.x, h = blockIdx.y, k = threadIdx.x;
    float acc = 0.f;
    #pragma unroll
    for (int e = 0; e < 16; ++e)
        acc += timeb[b*16+e]*tadj[((long)e*HT_+h)*TT_ + k];
    dyn[((long)b*HT_+h)*TT_ + k] = acc;
}

// ---------------------------------------------------------------------------
// tem[b,h,d] = lrelu( sum_k dyn[b,h,k]*(s[b,k,d] + mask[k>>4]) )
// ---------------------------------------------------------------------------
__global__ __launch_bounds__(64) void k_tem(const float* __restrict__ dyn,
        const float* __restrict__ sbuf, float* __restrict__ tem){
    int b = blockIdx.x, h = blockIdx.y, d = threadIdx.x;
    const float* dr = dyn + ((long)b*HT_+h)*TT_;
    float acc = 0.f;
    for (int k = 0; k < TT_; ++k){
        float hy = sbuf[((long)b*TT_ + k)*64 + d] + (float)((k>>4)+1)*(1.f/12.f);
        acc += dr[k]*hy;
    }
    tem[((long)b*HT_+h)*64+d] = lrelu_(acc);
}

// ---------------------------------------------------------------------------
// ret[b,k,d] = lrelu(sum_h dyn[b,h,k]*tem[b,h,d]) + s[b,k,d];  v2 = squash(ret)
// ---------------------------------------------------------------------------
__global__ __launch_bounds__(64) void k_retv2(const float* __restrict__ dyn,
        const float* __restrict__ tem, const float* __restrict__ sbuf,
        float* __restrict__ v2){
    int b = blockIdx.x, k = blockIdx.y, d = threadIdx.x;
    float acc = 0.f;
    for (int h = 0; h < HT_; ++h)
        acc += dyn[((long)b*HT_+h)*TT_+k] * tem[((long)b*HT_+h)*64+d];
    float r = lrelu_(acc) + sbuf[((long)b*TT_+k)*64+d];
    float sn = wredsum(r*r);
    float sc = (sn/(1.f+sn))/(sqrtf(sn)+1e-8f);
    v2[((long)b*TT_+k)*64+d] = r*sc;
}

// ---------------------------------------------------------------------------
// final: per node n: w_sp[n]=ne@wspa in LDS; loop bt:
//   recon[i]=sum_h c[bt,h,n]*v2[bt,h,i];  out = lrelu(recon@w_sp + b_sp + x)
// ---------------------------------------------------------------------------
__global__ __launch_bounds__(256) void k_final(const float* __restrict__ x,
        const float* __restrict__ ne, const float* __restrict__ wspa,
        const float* __restrict__ bspa, const float* __restrict__ cbuf,
        const float* __restrict__ v2, float* __restrict__ out){
    __shared__ __align__(16) float wsp[64*65];
    __shared__ float bsp[64];
    __shared__ float rec[4][64];
    int n = blockIdx.x, t = threadIdx.x;
    int g = t>>6, d = t&63;
    float nl[16];
    #pragma unroll
    for (int e = 0; e < 16; ++e) nl[e] = ne[n*16+e];
    #pragma unroll
    for (int j = 0; j < 16; ++j){
        int io = j*256 + t;
        float a = 0.f;
        #pragma unroll
        for (int e = 0; e < 16; ++e) a += nl[e]*wspa[(long)e*4096 + io];
        wsp[(io>>6)*65 + (io&63)] = a;
    }
    if (t < 64){
        float a = 0.f;
        #pragma unroll
        for (int e = 0; e < 16; ++e) a += nl[e]*bspa[e*64+t];
        bsp[t] = a;
    }
    __syncthreads();
    for (int btg = 0; btg < 48; ++btg){
        int bt = btg*4 + g;
        float ri = 0.f;
        #pragma unroll
        for (int h = 0; h < 16; ++h)
            ri += cbuf[((long)bt*HS_+h)*N_+n] * v2[((long)bt*HS_+h)*64 + d];
        rec[g][d] = ri;
        __syncthreads();
        float o = bsp[d];
        #pragma unroll
        for (int i = 0; i < 64; ++i) o += rec[g][i]*wsp[i*65+d];
        float xr = x[((long)bt*N_+n)*64 + d];
        out[((long)bt*N_+n)*64 + d] = lrelu_(o + xr);
        __syncthreads();
    }
}

extern "C" void kernel_launch(void* const* d_in, const int* in_sizes, int n_in,
                              void* d_out, int out_size, void* d_ws, size_t ws_size,
                              hipStream_t stream) {
    const float* x     = (const float*)d_in[0];
    const float* ne    = (const float*)d_in[1];
    const float* timeb = (const float*)d_in[2];
    const float* teb   = (const float*)d_in[3];
    const float* Wp    = (const float*)d_in[4];
    const float* bp    = (const float*)d_in[5];
    const float* tadj  = (const float*)d_in[6];
    const float* adj   = (const float*)d_in[7];
    const float* wspa  = (const float*)d_in[8];
    const float* bspa  = (const float*)d_in[9];

    float* out    = (float*)d_out;
    float* outc   = out  + (size_t)BT_*N_*64;      // c:   [BT,HS,N]
    float* outdyn = outc + (size_t)BT_*HS_*N_;     // dyn: [B,HT,TT]

    float* ws   = (float*)d_ws;
    float* P    = ws;                                  // [BT,N,64]
    float* dadj = P    + (size_t)BT_*N_*64;            // [BT,HS,N]
    float* bbuf = dadj + (size_t)BT_*HS_*N_;           // [BT,HS,N]
    float* v1   = bbuf + (size_t)BT_*HS_*N_;           // [BT,HS,64]
    float* vv   = v1   + (size_t)BT_*HS_*64;           // [BT,HS,64]  (later reused as v2)
    float* sbuf = vv   + (size_t)BT_*HS_*64;           // [BT,HS,64]
    float* tem  = sbuf + (size_t)BT_*HS_*64;           // [B,HT,64]

    hipMemsetAsync(bbuf, 0, (size_t)BT_*HS_*N_*sizeof(float), stream);

    k_P<<<dim3(BT_*N_/64), 256, 0, stream>>>(x, Wp, bp, P);
    k_dadj<<<dim3(BT_, HS_), 256, 0, stream>>>(teb, adj, dadj);

    // test1 -> v1 = squash(test1)
    k_route<<<dim3(BT_), 256, 0, stream>>>(dadj, nullptr, P, nullptr, v1, nullptr, 0);

    // 3 routing iterations
    for (int it = 0; it < 3; ++it){
        k_route<<<dim3(BT_), 256, 0, stream>>>(bbuf, nullptr, P, v1, vv, nullptr, 1);
        k_bupd<<<dim3(BT_, 8), 256, 0, stream>>>(P, vv, bbuf);
    }

    // final c (written to output) and s
    k_route<<<dim3(BT_), 256, 0, stream>>>(bbuf, dadj, P, nullptr, sbuf, outc, 2);

    k_dyn<<<dim3(B_, HT_), 192, 0, stream>>>(timeb, tadj, outdyn);
    k_tem<<<dim3(B_, HT_), 64, 0, stream>>>(outdyn, sbuf, tem);
    k_retv2<<<dim3(B_, TT_), 64, 0, stream>>>(outdyn, tem, sbuf, vv);

    k_final<<<dim3(N_), 256, 0, stream>>>(x, ne, wspa, bspa, outc, vv, out);
}